// Round 1
// baseline (440.824 us; speedup 1.0000x reference)
//
#include <hip/hip_runtime.h>
#include <math.h>

#define TS 32
#define TW 42          // TS + 2*HALO
#define HALO 5
#define HW 65536
#define C1F 1.0e-4f
#define C2F 9.0e-4f

__device__ __constant__ float G11[11] = {
  0.0010284f, 0.0075987f, 0.0360008f, 0.1093607f, 0.2130056f,
  0.2660118f, 0.2130056f, 0.1093607f, 0.0360008f, 0.0075987f, 0.0010284f
};

// ws layout: float accum[0..4] = {abs_dc, ssim, hdiff, vdiff, cos};
//            unsigned mask count at byte offset 24; hist (B*192 uint) at byte 64.

__global__ __launch_bounds__(256)
void ssim_tv_kernel(const float* __restrict__ dz_g, const float* __restrict__ cw_g,
                    const float* __restrict__ mk_g, float* __restrict__ accum)
{
  __shared__ float sd[TW*TW];
  __shared__ float sc[TW*TW];
  __shared__ float ht[5][TW*TS];
  __shared__ float red[16];

  int bid = blockIdx.x;
  int tx = bid & 7; bid >>= 3;
  int ty = bid & 7; bid >>= 3;
  int plane = bid;              // b*3 + c, 0..B*3-1
  int b = plane / 3;

  const float* dz = dz_g + plane * HW;
  const float* cw = cw_g + plane * HW;
  const float* mk = mk_g + b * HW;

  int row0 = ty*TS - HALO, col0 = tx*TS - HALO;
  int tid = threadIdx.x;

  // stage d = dehaze_img*mask, c = CleanWater*mask with zero halo (matches zero-pad conv)
  for (int i = tid; i < TW*TW; i += 256) {
    int r = i / TW, cl = i - r*TW;
    int gr = row0 + r, gc = col0 + cl;
    float d = 0.f, c = 0.f;
    if ((unsigned)gr < 256u && (unsigned)gc < 256u) {
      int o = gr*256 + gc;
      float m = mk[o];
      d = dz[o]*m;
      c = cw[o]*m;
    }
    sd[i] = d; sc[i] = c;
  }
  __syncthreads();

  // horizontal 11-tap conv of 5 fields (mu1, mu2, d*d, c*c, d*c)
  for (int i = tid; i < TW*TS; i += 256) {
    int r = i >> 5, cl = i & 31;
    const float* pd = sd + r*TW + cl;
    const float* pc = sc + r*TW + cl;
    float m1=0.f,m2=0.f,s11=0.f,s22=0.f,s12=0.f;
#pragma unroll
    for (int k = 0; k < 11; ++k) {
      float w = G11[k];
      float a = pd[k], bb = pc[k];
      m1  = fmaf(w, a,  m1);
      m2  = fmaf(w, bb, m2);
      s11 = fmaf(w*a, a,  s11);
      s22 = fmaf(w*bb, bb, s22);
      s12 = fmaf(w*a, bb, s12);
    }
    ht[0][i]=m1; ht[1][i]=m2; ht[2][i]=s11; ht[3][i]=s22; ht[4][i]=s12;
  }
  __syncthreads();

  float ssim_sum=0.f, abs_sum=0.f, h_sum=0.f, v_sum=0.f;
#pragma unroll
  for (int it = 0; it < 4; ++it) {
    int pix = it*256 + tid;
    int row = pix >> 5, col = pix & 31;
    float mu1=0.f,mu2=0.f,x11=0.f,x22=0.f,x12=0.f;
#pragma unroll
    for (int k = 0; k < 11; ++k) {
      float w = G11[k];
      int o = (row+k)*TS + col;
      mu1 = fmaf(w, ht[0][o], mu1);
      mu2 = fmaf(w, ht[1][o], mu2);
      x11 = fmaf(w, ht[2][o], x11);
      x22 = fmaf(w, ht[3][o], x22);
      x12 = fmaf(w, ht[4][o], x12);
    }
    float mu1s = mu1*mu1, mu2s = mu2*mu2, mu12 = mu1*mu2;
    float num = (2.f*mu12 + C1F) * (2.f*(x12 - mu12) + C2F);
    float den = (mu1s + mu2s + C1F) * ((x11 - mu1s) + (x22 - mu2s) + C2F);
    ssim_sum += num / den;

    // fused L_dehaze + TV on the interior pixel (neighbors live in the halo)
    int lr = row + HALO, lc = col + HALO;
    float dv = sd[lr*TW + lc];
    abs_sum += fabsf(dv - sc[lr*TW + lc]);
    if (col0 + lc < 255) h_sum += fabsf(dv - sd[lr*TW + lc + 1]);
    if (row0 + lr < 255) v_sum += fabsf(dv - sd[(lr+1)*TW + lc]);
  }

#pragma unroll
  for (int off = 32; off > 0; off >>= 1) {
    abs_sum  += __shfl_down(abs_sum,  off);
    ssim_sum += __shfl_down(ssim_sum, off);
    h_sum    += __shfl_down(h_sum,    off);
    v_sum    += __shfl_down(v_sum,    off);
  }
  if ((tid & 63) == 0) {
    int w = tid >> 6;
    red[w*4+0]=abs_sum; red[w*4+1]=ssim_sum; red[w*4+2]=h_sum; red[w*4+3]=v_sum;
  }
  __syncthreads();
  if (tid < 4) {
    float s = red[tid] + red[4+tid] + red[8+tid] + red[12+tid];
    atomicAdd(&accum[tid], s);
  }
}

__global__ __launch_bounds__(256)
void cos_hist_kernel(const float* __restrict__ pr, const float* __restrict__ gt,
                     const float* __restrict__ mk, float* __restrict__ accum,
                     unsigned* __restrict__ mcount, unsigned* __restrict__ hist)
{
  __shared__ unsigned lh[192];
  __shared__ float redf[4];
  __shared__ unsigned redi[4];
  int tid = threadIdx.x;
  for (int i = tid; i < 192; i += 256) lh[i] = 0u;
  __syncthreads();

  int b = blockIdx.x >> 4;
  int chunk = blockIdx.x & 15;
  const float* p = pr + b*3*HW;
  const float* g = gt + b*3*HW;
  const float* m = mk + b*HW;

  float cos_sum = 0.f;
  unsigned cnt = 0u;
  int base = chunk*4096;
  for (int it = 0; it < 16; ++it) {
    int pi = base + it*256 + tid;
    float mv = m[pi];
    float g0 = g[pi], g1 = g[HW+pi], g2 = g[2*HW+pi];
    float p0 = p[pi]*mv, p1 = p[HW+pi]*mv, p2 = p[2*HW+pi]*mv;

    // histogram of raw ground_truth: idx = floor(((x*2-1)+1)*0.5*64), clip [0,63]
    {
      float v0 = g0*2.f-1.f, v1 = g1*2.f-1.f, v2 = g2*2.f-1.f;
      int i0 = (int)floorf((v0+1.f)*0.5f*64.f);
      int i1 = (int)floorf((v1+1.f)*0.5f*64.f);
      int i2 = (int)floorf((v2+1.f)*0.5f*64.f);
      i0 = min(max(i0,0),63); i1 = min(max(i1,0),63); i2 = min(max(i2,0),63);
      atomicAdd(&lh[i0],     1u);
      atomicAdd(&lh[64+i1],  1u);
      atomicAdd(&lh[128+i2], 1u);
    }

    // cosine term, literal per reference
    float np = sqrtf(p0*p0 + p1*p1 + p2*p2);
    float inv = 1.f / fmaxf(np, 1e-12f);
    float q0=p0*inv, q1=p1*inv, q2=p2*inv;
    float t0 = (g0*mv*2.f - 1.f)*mv;
    float t1 = (g1*mv*2.f - 1.f)*mv;
    float t2 = (g2*mv*2.f - 1.f)*mv;
    float dot = q0*t0 + q1*t1 + q2*t2;
    float n1 = fmaxf(sqrtf(q0*q0+q1*q1+q2*q2), 1e-8f);
    float n2 = fmaxf(sqrtf(t0*t0+t1*t1+t2*t2), 1e-8f);
    cos_sum += 1.f - dot/(n1*n2);
    cnt += (mv != 0.f) ? 1u : 0u;   // mask is exactly {0.0, 1.0}
  }

#pragma unroll
  for (int off = 32; off > 0; off >>= 1) {
    cos_sum += __shfl_down(cos_sum, off);
    cnt     += __shfl_down(cnt,     off);
  }
  if ((tid & 63) == 0) { redf[tid>>6] = cos_sum; redi[tid>>6] = cnt; }
  __syncthreads();
  if (tid == 0) {
    atomicAdd(&accum[4], redf[0]+redf[1]+redf[2]+redf[3]);
    atomicAdd(mcount, redi[0]+redi[1]+redi[2]+redi[3]);
  }
  for (int i = tid; i < 192; i += 256) {
    unsigned v = lh[i];
    if (v) atomicAdd(&hist[b*192 + i], v);
  }
}

__global__ __launch_bounds__(256)
void finalize_kernel(const float* __restrict__ nh, const unsigned* __restrict__ hist,
                     const float* __restrict__ accum, const unsigned* __restrict__ mcount,
                     float* __restrict__ out, int B)
{
  __shared__ float red[4];
  int tid = threadIdx.x;
  int n = B*192;
  float hs = 0.f;
  for (int i = tid; i < n; i += 256)
    hs += fabsf(nh[i] - (float)hist[i] * (1.f/65536.f));
#pragma unroll
  for (int off = 32; off > 0; off >>= 1) hs += __shfl_down(hs, off);
  if ((tid & 63) == 0) red[tid>>6] = hs;
  __syncthreads();
  if (tid == 0) {
    float hist_sum = red[0]+red[1]+red[2]+red[3];
    float Np = (float)B * 3.f * 65536.f;
    float L_dehaze = accum[0] / Np;
    float L_ssim = 1.f - accum[1] / Np;
    float L_tv = accum[2] / ((float)B*3.f*256.f*255.f)
               + accum[3] / ((float)B*3.f*255.f*256.f);
    float L_hist = hist_sum / (float)n;
    float M = (float)(*mcount);
    float back = (float)B * 65536.f - M;
    float L_normal = (accum[4] - back) / M;
    out[0] = 10.f*L_dehaze + L_ssim + L_tv + L_hist + 100.f*L_normal;
  }
}

extern "C" void kernel_launch(void* const* d_in, const int* in_sizes, int n_in,
                              void* d_out, int out_size, void* d_ws, size_t ws_size,
                              hipStream_t stream)
{
  const float* predict = (const float*)d_in[0];
  const float* gt      = (const float*)d_in[1];
  const float* dehaze  = (const float*)d_in[2];
  const float* cleanw  = (const float*)d_in[3];
  const float* nh      = (const float*)d_in[4];
  const float* mask    = (const float*)d_in[5];
  int B = in_sizes[0] / (3*HW);

  float* accum      = (float*)d_ws;
  unsigned* mcount  = (unsigned*)((char*)d_ws + 24);
  unsigned* hist    = (unsigned*)((char*)d_ws + 64);

  hipMemsetAsync(d_ws, 0, 64 + (size_t)B*192*4, stream);

  ssim_tv_kernel<<<B*3*64, 256, 0, stream>>>(dehaze, cleanw, mask, accum);
  cos_hist_kernel<<<B*16, 256, 0, stream>>>(predict, gt, mask, accum, mcount, hist);
  finalize_kernel<<<1, 256, 0, stream>>>(nh, hist, accum, mcount, (float*)d_out, B);
}

// Round 2
// 386.204 us; speedup vs baseline: 1.1414x; 1.1414x over previous
//
#include <hip/hip_runtime.h>
#include <math.h>

#define HW 65536
#define C1F 1.0e-4f
#define C2F 9.0e-4f
#define SROW 44            // padded LDS row stride (16B-aligned rows)
#define HTW 32

__device__ __constant__ float G11[11] = {
  0.0010284f, 0.0075987f, 0.0360008f, 0.1093607f, 0.2130056f,
  0.2660118f, 0.2130056f, 0.1093607f, 0.0360008f, 0.0075987f, 0.0010284f
};

// ws layout: float accum[0..4] = {abs_dc, ssim, hdiff, vdiff, cos};
//            unsigned mask count at byte 24; hist (B*192 uint) at byte 64.

__global__ __launch_bounds__(256)
void ssim_tv_kernel(const float* __restrict__ dz_g, const float* __restrict__ cw_g,
                    const float* __restrict__ mk_g, float* __restrict__ accum)
{
  __shared__ __align__(16) float sd[42*SROW];
  __shared__ __align__(16) float sc[42*SROW];
  __shared__ __align__(16) float ht[5][42*HTW];
  __shared__ float red[16];

  int bid = blockIdx.x;
  int tx = bid & 7; bid >>= 3;
  int ty = bid & 7; bid >>= 3;
  int plane = bid;              // b*3 + c
  int b = plane / 3;

  const float* dz = dz_g + (size_t)plane * HW;
  const float* cw = cw_g + (size_t)plane * HW;
  const float* mk = mk_g + (size_t)b * HW;

  int row0 = ty*32 - 5, col0 = tx*32 - 5;
  int tid = threadIdx.x;

  float abs_sum = 0.f, h_sum = 0.f, v_sum = 0.f, ssim_sum = 0.f;

  // ---- stage d=dz*m, c=cw*m (zero halo + zero pad cols); fold L1 term in ----
  for (int i = tid; i < 42*SROW; i += 256) {
    int r = i / SROW, c = i - r*SROW;
    float d = 0.f, cc = 0.f;
    if (c < 42) {
      int gr = row0 + r, gc = col0 + c;
      if ((unsigned)gr < 256u && (unsigned)gc < 256u) {
        int o = gr*256 + gc;
        float m = mk[o];
        d = dz[o]*m; cc = cw[o]*m;
      }
      if (r >= 5 && r < 37 && c >= 5 && c < 37)
        abs_sum += fabsf(d - cc);
    }
    sd[i] = d; sc[i] = cc;
  }
  __syncthreads();

  // ---- horizontal 11-tap: 336 runs of 4 outputs, float4 LDS I/O; fold h-TV ----
  for (int ri = tid; ri < 336; ri += 256) {
    int r = ri >> 3;
    int c0 = (ri & 7) << 2;
    const float4* pa = (const float4*)(sd + r*SROW + c0);
    const float4* pb = (const float4*)(sc + r*SROW + c0);
    float wa[16], wb[16];
    ((float4*)wa)[0] = pa[0]; ((float4*)wa)[1] = pa[1];
    ((float4*)wa)[2] = pa[2]; ((float4*)wa)[3] = pa[3];
    ((float4*)wb)[0] = pb[0]; ((float4*)wb)[1] = pb[1];
    ((float4*)wb)[2] = pb[2]; ((float4*)wb)[3] = pb[3];
    float m1[4] = {0,0,0,0}, m2[4] = {0,0,0,0};
    float s11[4] = {0,0,0,0}, s22[4] = {0,0,0,0}, s12[4] = {0,0,0,0};
#pragma unroll
    for (int k = 0; k < 11; ++k) {
      float w = G11[k];
#pragma unroll
      for (int j = 0; j < 4; ++j) {
        float a = wa[j+k], bb = wb[j+k];
        float waj = w*a, wbj = w*bb;
        m1[j]  = fmaf(w, a,  m1[j]);
        m2[j]  = fmaf(w, bb, m2[j]);
        s11[j] = fmaf(waj, a,  s11[j]);
        s22[j] = fmaf(wbj, bb, s22[j]);
        s12[j] = fmaf(waj, bb, s12[j]);
      }
    }
    int o = r*HTW + c0;
    *(float4*)&ht[0][o] = make_float4(m1[0],m1[1],m1[2],m1[3]);
    *(float4*)&ht[1][o] = make_float4(m2[0],m2[1],m2[2],m2[3]);
    *(float4*)&ht[2][o] = make_float4(s11[0],s11[1],s11[2],s11[3]);
    *(float4*)&ht[3][o] = make_float4(s22[0],s22[1],s22[2],s22[3]);
    *(float4*)&ht[4][o] = make_float4(s12[0],s12[1],s12[2],s12[3]);
    if (r >= 5 && r < 37) {
#pragma unroll
      for (int j = 0; j < 4; ++j) {
        if (tx*32 + c0 + j < 255)
          h_sum += fabsf(wa[j+5] - wa[j+6]);
      }
    }
  }
  __syncthreads();

  // ---- vertical 11-tap, 4-row register blocking + SSIM map + v-TV ----
  {
    int col = tid & 31;
    int r0 = (tid >> 5) << 2;     // 0,4,...,28
    float acc[5][4];
#pragma unroll
    for (int f = 0; f < 5; ++f)
#pragma unroll
      for (int j = 0; j < 4; ++j) acc[f][j] = 0.f;
#pragma unroll
    for (int k = 0; k < 14; ++k) {
      int o = (r0 + k)*HTW + col;
#pragma unroll
      for (int f = 0; f < 5; ++f) {
        float v = ht[f][o];
#pragma unroll
        for (int j = 0; j < 4; ++j) {
          int t = k - j;
          if (t >= 0 && t < 11)
            acc[f][j] = fmaf(G11[t], v, acc[f][j]);
        }
      }
    }
#pragma unroll
    for (int j = 0; j < 4; ++j) {
      float mu1 = acc[0][j], mu2 = acc[1][j];
      float x11 = acc[2][j], x22 = acc[3][j], x12 = acc[4][j];
      float mu1s = mu1*mu1, mu2s = mu2*mu2, mu12 = mu1*mu2;
      float num = (2.f*mu12 + C1F) * (2.f*(x12 - mu12) + C2F);
      float den = (mu1s + mu2s + C1F) * ((x11 - mu1s) + (x22 - mu2s) + C2F);
      ssim_sum += num * __builtin_amdgcn_rcpf(den);
    }
    float sv[5];
#pragma unroll
    for (int k = 0; k < 5; ++k) sv[k] = sd[(r0+5+k)*SROW + col + 5];
#pragma unroll
    for (int j = 0; j < 4; ++j) {
      if (ty*32 + r0 + j < 255) v_sum += fabsf(sv[j] - sv[j+1]);
    }
  }

#pragma unroll
  for (int off = 32; off > 0; off >>= 1) {
    abs_sum  += __shfl_down(abs_sum,  off);
    ssim_sum += __shfl_down(ssim_sum, off);
    h_sum    += __shfl_down(h_sum,    off);
    v_sum    += __shfl_down(v_sum,    off);
  }
  if ((tid & 63) == 0) {
    int w = tid >> 6;
    red[w*4+0]=abs_sum; red[w*4+1]=ssim_sum; red[w*4+2]=h_sum; red[w*4+3]=v_sum;
  }
  __syncthreads();
  if (tid < 4) {
    float s = red[tid] + red[4+tid] + red[8+tid] + red[12+tid];
    atomicAdd(&accum[tid], s);
  }
}

__device__ __forceinline__ void cos_hist_px(float mv, float g0, float g1, float g2,
                                            float P0, float P1, float P2,
                                            float& cos_sum, unsigned& cnt,
                                            unsigned* lh)
{
  // histogram of raw ground_truth (literal index sequence)
  {
    float v0 = g0*2.f-1.f, v1 = g1*2.f-1.f, v2 = g2*2.f-1.f;
    int i0 = (int)floorf((v0+1.f)*0.5f*64.f);
    int i1 = (int)floorf((v1+1.f)*0.5f*64.f);
    int i2 = (int)floorf((v2+1.f)*0.5f*64.f);
    i0 = min(max(i0,0),63); i1 = min(max(i1,0),63); i2 = min(max(i2,0),63);
    atomicAdd(&lh[i0],     1u);
    atomicAdd(&lh[64+i1],  1u);
    atomicAdd(&lh[128+i2], 1u);
  }
  float p0 = P0*mv, p1 = P1*mv, p2 = P2*mv;
  float np2 = p0*p0 + p1*p1 + p2*p2;
  float inv = __builtin_amdgcn_rcpf(fmaxf(sqrtf(np2), 1e-12f));
  float q0 = p0*inv, q1 = p1*inv, q2 = p2*inv;
  float t0 = (g0*mv*2.f - 1.f)*mv;
  float t1 = (g1*mv*2.f - 1.f)*mv;
  float t2 = (g2*mv*2.f - 1.f)*mv;
  float dot = q0*t0 + q1*t1 + q2*t2;
  float n1 = fmaxf(sqrtf(q0*q0+q1*q1+q2*q2), 1e-8f);
  float n2 = fmaxf(sqrtf(t0*t0+t1*t1+t2*t2), 1e-8f);
  cos_sum += 1.f - dot * __builtin_amdgcn_rcpf(n1*n2);
  cnt += (mv != 0.f) ? 1u : 0u;
}

__global__ __launch_bounds__(256)
void cos_hist_kernel(const float* __restrict__ pr, const float* __restrict__ gt,
                     const float* __restrict__ mk, float* __restrict__ accum,
                     unsigned* __restrict__ mcount, unsigned* __restrict__ hist)
{
  __shared__ unsigned lh[192];
  __shared__ float redf[4];
  __shared__ unsigned redi[4];
  int tid = threadIdx.x;
  for (int i = tid; i < 192; i += 256) lh[i] = 0u;
  __syncthreads();

  int b = blockIdx.x >> 4;
  int chunk = blockIdx.x & 15;
  const float4* pv = (const float4*)(pr + (size_t)b*3*HW);
  const float4* gv = (const float4*)(gt + (size_t)b*3*HW);
  const float4* mv4 = (const float4*)(mk + (size_t)b*HW);
  int base4 = chunk*1024;       // 4096 px = 1024 float4s per chunk

  float cos_sum = 0.f;
  unsigned cnt = 0u;
  for (int it = 0; it < 4; ++it) {
    int i4 = base4 + it*256 + tid;
    float4 M  = mv4[i4];
    float4 G0 = gv[i4], G1 = gv[16384 + i4], G2 = gv[2*16384 + i4];
    float4 P0 = pv[i4], P1 = pv[16384 + i4], P2 = pv[2*16384 + i4];
    cos_hist_px(M.x, G0.x, G1.x, G2.x, P0.x, P1.x, P2.x, cos_sum, cnt, lh);
    cos_hist_px(M.y, G0.y, G1.y, G2.y, P0.y, P1.y, P2.y, cos_sum, cnt, lh);
    cos_hist_px(M.z, G0.z, G1.z, G2.z, P0.z, P1.z, P2.z, cos_sum, cnt, lh);
    cos_hist_px(M.w, G0.w, G1.w, G2.w, P0.w, P1.w, P2.w, cos_sum, cnt, lh);
  }

#pragma unroll
  for (int off = 32; off > 0; off >>= 1) {
    cos_sum += __shfl_down(cos_sum, off);
    cnt     += __shfl_down(cnt,     off);
  }
  if ((tid & 63) == 0) { redf[tid>>6] = cos_sum; redi[tid>>6] = cnt; }
  __syncthreads();
  if (tid == 0) {
    atomicAdd(&accum[4], redf[0]+redf[1]+redf[2]+redf[3]);
    atomicAdd(mcount, redi[0]+redi[1]+redi[2]+redi[3]);
  }
  for (int i = tid; i < 192; i += 256) {
    unsigned v = lh[i];
    if (v) atomicAdd(&hist[b*192 + i], v);
  }
}

__global__ __launch_bounds__(256)
void finalize_kernel(const float* __restrict__ nh, const unsigned* __restrict__ hist,
                     const float* __restrict__ accum, const unsigned* __restrict__ mcount,
                     float* __restrict__ out, int B)
{
  __shared__ float red[4];
  int tid = threadIdx.x;
  int n = B*192;
  float hs = 0.f;
  for (int i = tid; i < n; i += 256)
    hs += fabsf(nh[i] - (float)hist[i] * (1.f/65536.f));
#pragma unroll
  for (int off = 32; off > 0; off >>= 1) hs += __shfl_down(hs, off);
  if ((tid & 63) == 0) red[tid>>6] = hs;
  __syncthreads();
  if (tid == 0) {
    float hist_sum = red[0]+red[1]+red[2]+red[3];
    float Np = (float)B * 3.f * 65536.f;
    float L_dehaze = accum[0] / Np;
    float L_ssim = 1.f - accum[1] / Np;
    float L_tv = accum[2] / ((float)B*3.f*256.f*255.f)
               + accum[3] / ((float)B*3.f*255.f*256.f);
    float L_hist = hist_sum / (float)n;
    float M = (float)(*mcount);
    float back = (float)B * 65536.f - M;
    float L_normal = (accum[4] - back) / M;
    out[0] = 10.f*L_dehaze + L_ssim + L_tv + L_hist + 100.f*L_normal;
  }
}

extern "C" void kernel_launch(void* const* d_in, const int* in_sizes, int n_in,
                              void* d_out, int out_size, void* d_ws, size_t ws_size,
                              hipStream_t stream)
{
  const float* predict = (const float*)d_in[0];
  const float* gt      = (const float*)d_in[1];
  const float* dehaze  = (const float*)d_in[2];
  const float* cleanw  = (const float*)d_in[3];
  const float* nh      = (const float*)d_in[4];
  const float* mask    = (const float*)d_in[5];
  int B = in_sizes[0] / (3*HW);

  float* accum      = (float*)d_ws;
  unsigned* mcount  = (unsigned*)((char*)d_ws + 24);
  unsigned* hist    = (unsigned*)((char*)d_ws + 64);

  hipMemsetAsync(d_ws, 0, 64 + (size_t)B*192*4, stream);

  ssim_tv_kernel<<<B*3*64, 256, 0, stream>>>(dehaze, cleanw, mask, accum);
  cos_hist_kernel<<<B*16, 256, 0, stream>>>(predict, gt, mask, accum, mcount, hist);
  finalize_kernel<<<1, 256, 0, stream>>>(nh, hist, accum, mcount, (float*)d_out, B);
}